// Round 7
// baseline (269.914 us; speedup 1.0000x reference)
//
#include <hip/hip_runtime.h>
#include <stdint.h>

// QuantizedConv2d int8 implicit GEMM via MFMA i32_16x16x64_i8.
// N=32, C_in=128, H=W=56, C_out=256, 3x3, pad 1, stride 1.
// Output int8 values stored as int32 (harness reads integer outputs as np.int32).
//
// R7: PADDED input layout xp2[n][58][64][128] (zero h/w border rows materialized
// in prep) -> K-loop is 100% branch-free (no predicates/cndmask/zero-page), so
// loads pipeline; keep 1-tap-ahead register prefetch, XCD swizzle (R6: FETCH
// 7.5 MB), 36 KB B-LDS (co=32) at 3 blocks/CU.

#define NB 32
#define CI 128
#define HH 56
#define WW 56
#define CO 256
#define SPA (HH * WW)              // 3136; 64 | 3136 -> wave tiles never cross n
#define HP 58                      // padded h: index h+1, rows 0 and 57 are zero
#define WP 64                      // padded w: index w+1, cols 0 and 57..63 zero
#define XP2_BYTES (NB * HP * WP * CI)      // 15204352
#define BP_BYTES (8 * 72 * 32 * 16)        // 294912

typedef int v4i __attribute__((ext_vector_type(4)));

// ---- prep ----
// blocks [0,1792): pack one (n,h) data row -> padded NHWC int8
// blocks [1792,1856): zero rows (h_idx 0 and 57 per image)
// blocks [1856,2112): weight pack + BG table
__global__ __launch_bounds__(256) void prep_kernel(
    const int* __restrict__ x, const int* __restrict__ wgt,
    const int* __restrict__ bias, const int* __restrict__ zpi,
    int8_t* __restrict__ xp2, int8_t* __restrict__ bp, int* __restrict__ BG)
{
    __shared__ int sm[1824];
    const int tid = threadIdx.x, bid = blockIdx.x;

    if (bid < HH * NB) {
        // ---- pack x row: int32 NCHW -> int8 padded NHWC ----
        const int n = bid / HH, h = bid % HH;
        #pragma unroll
        for (int it = 0; it < 7; ++it) {
            int j = tid + it * 256;                 // 1792 = 128 ci x 14 w4
            int ci = j / 14, w4 = j - ci * 14;
            const v4i v = *(const v4i*)(x + ((n * CI + ci) * HH + h) * WW + w4 * 4);
            sm[w4 * 130 + ci] = (v.x & 255) | ((v.y & 255) << 8) |
                                ((v.z & 255) << 16) | (v.w << 24);
        }
        __syncthreads();
        int* od = (int*)xp2 + (n * HP + h + 1) * (WP * CI / 4);  // 2048 dwords/row
        #pragma unroll
        for (int it = 0; it < 8; ++it) {
            int j = tid + it * 256;                 // j = widx*32 + ci4
            int widx = j >> 5, ci4 = j & 31;
            int val = 0;
            if (widx >= 1 && widx <= WW) {          // w = widx-1 in-image
                int w = widx - 1;
                int base = (w >> 2) * 130 + ci4 * 4;
                int sh = (w & 3) * 8;
                int d0 = sm[base], d1 = sm[base + 1], d2 = sm[base + 2], d3 = sm[base + 3];
                val = ((d0 >> sh) & 0xff) | (((d1 >> sh) & 0xff) << 8) |
                      (((d2 >> sh) & 0xff) << 16) | ((d3 >> sh) << 24);
            }
            od[j] = val;
        }
    } else if (bid < HH * NB + 2 * NB) {
        // ---- zero border h-rows ----
        const int z = bid - HH * NB;
        const int n = z >> 1, hidx = (z & 1) ? (HP - 1) : 0;
        int* od = (int*)xp2 + (n * HP + hidx) * (WP * CI / 4);
        #pragma unroll
        for (int it = 0; it < 8; ++it) od[tid + it * 256] = 0;
    } else {
        // ---- pack w for one co + BG[co][9] ----
        const int co = bid - (HH * NB + 2 * NB);
        const int co32 = co >> 5, col = co & 31;
        for (int j = tid; j < 1152; j += 256) sm[j] = wgt[co * 1152 + j];  // [ci][9]
        __syncthreads();
        for (int j = tid; j < 288; j += 256) {      // 9t x 2c64 x 4q x 4j4
            int j4 = j & 3, q = (j >> 2) & 3, c64 = (j >> 4) & 1, t = j >> 5;
            int ci = c64 * 64 + q * 16 + j4 * 4;
            int b0 = sm[(ci + 0) * 9 + t] & 255, b1 = sm[(ci + 1) * 9 + t] & 255;
            int b2 = sm[(ci + 2) * 9 + t] & 255, b3 = sm[(ci + 3) * 9 + t];
            ((int*)bp)[((co32 * 72 + (t * 2 + c64) * 4 + q) * 32 + col) * 4 + j4] =
                b0 | (b1 << 8) | (b2 << 16) | (b3 << 24);
        }
        if (tid < 9) {                              // per-tap weight sums
            int s = 0;
            for (int ci = 0; ci < CI; ++ci) s += sm[ci * 9 + tid];
            sm[1152 + tid] = s;
        }
        __syncthreads();
        if (tid < 9) {                              // border-class -> BG
            int hc = tid / 3, wc = tid - hc * 3;
            int dlo = (hc == 0) ? 1 : 0, dhi = (hc == 2) ? 1 : 2;
            int clo = (wc == 0) ? 1 : 0, chi = (wc == 2) ? 1 : 2;
            int s = 0;
            for (int dr = dlo; dr <= dhi; ++dr)
                for (int dc = clo; dc <= chi; ++dc) s += sm[1152 + dr * 3 + dc];
            BG[co * 9 + tid] = bias[co] - (*zpi) * s;
        }
    }
}

// ---- main: block = 256 M x 32 co, 4 waves of 64 M x 32 co; barrier-free K ----
__global__ __launch_bounds__(256, 3) void qconv_mfma(
    const int8_t* __restrict__ xp2, const int8_t* __restrict__ bp,
    const int* __restrict__ BG,
    const float* __restrict__ si, const float* __restrict__ sw,
    const float* __restrict__ so, const int* __restrict__ zpo,
    int* __restrict__ out)
{
    const int tid  = threadIdx.x, lane = tid & 63, wid = tid >> 6;
    const int quad = lane >> 4, lo16 = lane & 15;
    // XCD swizzle (verified R6: FETCH 24->7.5 MB): 8 consecutive same-XCD
    // blocks share an M-range and sweep the 8 co-blocks.
    const int bid  = blockIdx.x;
    const int xcd  = bid & 7, co32 = (bid >> 3) & 7, mi = bid >> 6;
    const int mbase  = (xcd * 49 + mi) * 256 + wid * 64;
    const int cobase = co32 * 32;

    __shared__ char smem[36 * 1024];        // B; epilogue aliases it

    #pragma unroll
    for (int k = 0; k < 9; ++k) {           // stage B once (36 KB/block)
        const int off = k * 4096 + wid * 1024;
        __builtin_amdgcn_global_load_lds(
            (const __attribute__((address_space(1))) void*)
                (bp + co32 * 36864 + off + lane * 16),
            (__attribute__((address_space(3))) void*)(smem + off),
            16, 0, 0);
    }

    const int nS   = mbase / SPA;           // wave-uniform (64 | 3136)
    const int remS = mbase - nS * SPA;
    int base0[4];
    #pragma unroll
    for (int mt = 0; mt < 4; ++mt) {        // padded addr of tap (dr=0,dc=0)
        const int rm = remS + mt * 16 + lo16;
        const int h = rm / WW, w = rm - h * WW;
        base0[mt] = ((nS * HP + h) * WP + w) * 128 + quad * 16;
    }

    v4i acc[4][2];
    #pragma unroll
    for (int mt = 0; mt < 4; ++mt) {
        acc[mt][0] = (v4i){0, 0, 0, 0}; acc[mt][1] = (v4i){0, 0, 0, 0};
    }

    v4i aC[4][2], aN[4][2];
    #pragma unroll
    for (int mt = 0; mt < 4; ++mt) {        // tap 0: offset 0
        aC[mt][0] = *(const v4i*)(xp2 + base0[mt]);
        aC[mt][1] = *(const v4i*)(xp2 + base0[mt] + 64);
    }
    __syncthreads();                        // B staged

    #pragma unroll
    for (int t = 0; t < 9; ++t) {
        if (t < 8) {                        // branch-free prefetch of tap t+1
            const int tt = t + 1;
            const int off = ((tt / 3) * WP + (tt % 3)) * 128;   // compile-time
            #pragma unroll
            for (int mt = 0; mt < 4; ++mt) {
                aN[mt][0] = *(const v4i*)(xp2 + base0[mt] + off);
                aN[mt][1] = *(const v4i*)(xp2 + base0[mt] + off + 64);
            }
        }
        #pragma unroll
        for (int c = 0; c < 2; ++c) {
            const int ub = ((t * 2 + c) * 4 + quad) * 512 + lo16 * 16;
            #pragma unroll
            for (int ct = 0; ct < 2; ++ct) {
                v4i b = *(const v4i*)(smem + ub + ct * 256);
                #pragma unroll
                for (int mt = 0; mt < 4; ++mt)
                    acc[mt][ct] = __builtin_amdgcn_mfma_i32_16x16x64_i8(
                        aC[mt][c], b, acc[mt][ct], 0, 0, 0);
            }
        }
        #pragma unroll
        for (int mt = 0; mt < 4; ++mt) {
            aC[mt][0] = aN[mt][0]; aC[mt][1] = aN[mt][1];
        }
    }

    // ---- epilogue: requant + LDS transpose (aliased onto dead B) ----
    const float rs = (*si) * (*sw) / (*so);
    const float zo = (float)(*zpo);

    __syncthreads();                        // all waves done reading B
    int* lt = (int*)smem + wid * 2304;      // 32 co x 66-dword rows, 8448 B

    #pragma unroll
    for (int mt = 0; mt < 4; ++mt) {
        int cls[4];
        #pragma unroll
        for (int i = 0; i < 4; ++i) {
            const int rm = remS + mt * 16 + quad * 4 + i;   // C/D row = quad*4+i
            const int h2 = rm / WW, w2 = rm - h2 * WW;
            const int hc = (h2 == 0) ? 0 : ((h2 == HH - 1) ? 2 : 1);
            const int wc = (w2 == 0) ? 0 : ((w2 == WW - 1) ? 2 : 1);
            cls[i] = hc * 3 + wc;
        }
        #pragma unroll
        for (int ct = 0; ct < 2; ++ct) {
            const int co = cobase + ct * 16 + lo16;         // C/D col = lane&15
            v4i vv;
            #pragma unroll
            for (int i = 0; i < 4; ++i) {
                int a = acc[mt][ct][i] + BG[co * 9 + cls[i]];
                float y = rintf((float)a * rs + zo);
                y = fminf(fmaxf(y, -128.f), 127.f);
                vv[i] = (int)y;
            }
            *(v4i*)(lt + (ct * 16 + lo16) * 66 + mt * 16 + quad * 4) = vv;
        }
    }
    // same-wave ds_write -> ds_read: in-order, no barrier

    #pragma unroll
    for (int cc = 0; cc < 8; ++cc) {
        const int col = cc * 4 + (lane >> 4);               // co_local 0..31
        const int m4  = (lane & 15) * 4;                    // 256-B runs
        v4i v = *(const v4i*)(lt + col * 66 + m4);
        const int oidx = (nS * CO + cobase + col) * SPA + remS + m4;
        *(v4i*)(out + oidx) = v;
    }
}

extern "C" void kernel_launch(void* const* d_in, const int* in_sizes, int n_in,
                              void* d_out, int out_size, void* d_ws, size_t ws_size,
                              hipStream_t stream) {
    const int*   x    = (const int*)d_in[0];
    const int*   wgt  = (const int*)d_in[1];
    const int*   bias = (const int*)d_in[2];
    const float* si   = (const float*)d_in[3];
    const float* sw   = (const float*)d_in[4];
    const float* so   = (const float*)d_in[5];
    const int*   zpi  = (const int*)d_in[6];
    const int*   zpo  = (const int*)d_in[7];
    int* out = (int*)d_out;

    int8_t* xp2 = (int8_t*)d_ws;
    int8_t* bp  = xp2 + XP2_BYTES;
    int*    bg  = (int*)(bp + BP_BYTES);

    prep_kernel<<<HH * NB + 2 * NB + CO, 256, 0, stream>>>(x, wgt, bias, zpi, xp2, bp, bg);
    qconv_mfma<<<8 * 8 * 49, 256, 0, stream>>>(xp2, bp, bg, si, sw, so, zpo, out);
}

// Round 8
// 230.975 us; speedup vs baseline: 1.1686x; 1.1686x over previous
//
#include <hip/hip_runtime.h>
#include <stdint.h>

// QuantizedConv2d int8 implicit GEMM via MFMA i32_16x16x64_i8.
// N=32, C_in=128, H=W=56, C_out=256, 3x3, pad 1, stride 1.
// Output int8 values stored as int32 (harness reads integer outputs as np.int32).
//
// R8: co=64/block (R4's best: halves L2 A-traffic vs co=32), padded A layout +
// XCD swizzle (R6/R7: FETCH 7.5 MB, branch-free K-loop), 3-tap row-group
// double-buffered A pipeline with __launch_bounds__(256,2) so the register
// allocator keeps the prefetch in VGPRs (R7 failure: VGPR=72, loads sunk).

#define NB 32
#define CI 128
#define HH 56
#define WW 56
#define CO 256
#define SPA (HH * WW)              // 3136; 32 | 3136 -> wave tiles never cross n
#define HP 58                      // padded h: image row h at index h+1
#define WP 64                      // padded w: image col w at index w+1
#define XP2_BYTES (NB * HP * WP * CI)      // 15204352
#define BP_BYTES (9 * 2 * 4 * CO * 16)     // 294912

typedef int v4i __attribute__((ext_vector_type(4)));

// ---- prep ----
// blocks [0,1792): pack one (n,h) row -> padded NHWC int8
// blocks [1792,1856): zero h-border rows
// blocks [1856,2112): weight pack + BG table
__global__ __launch_bounds__(256) void prep_kernel(
    const int* __restrict__ x, const int* __restrict__ wgt,
    const int* __restrict__ bias, const int* __restrict__ zpi,
    int8_t* __restrict__ xp2, int8_t* __restrict__ bp, int* __restrict__ BG)
{
    __shared__ int sm[1824];
    const int tid = threadIdx.x, bid = blockIdx.x;

    if (bid < HH * NB) {
        const int n = bid / HH, h = bid % HH;
        #pragma unroll
        for (int it = 0; it < 7; ++it) {
            int j = tid + it * 256;                 // 1792 = 128 ci x 14 w4
            int ci = j / 14, w4 = j - ci * 14;
            const v4i v = *(const v4i*)(x + ((n * CI + ci) * HH + h) * WW + w4 * 4);
            sm[w4 * 130 + ci] = (v.x & 255) | ((v.y & 255) << 8) |
                                ((v.z & 255) << 16) | (v.w << 24);
        }
        __syncthreads();
        int* od = (int*)xp2 + (n * HP + h + 1) * (WP * CI / 4);  // 2048 dwords/row
        #pragma unroll
        for (int it = 0; it < 8; ++it) {
            int j = tid + it * 256;                 // j = widx*32 + ci4
            int widx = j >> 5, ci4 = j & 31;
            int val = 0;
            if (widx >= 1 && widx <= WW) {
                int w = widx - 1;
                int base = (w >> 2) * 130 + ci4 * 4;
                int sh = (w & 3) * 8;
                val = ((sm[base] >> sh) & 0xff) | (((sm[base+1] >> sh) & 0xff) << 8) |
                      (((sm[base+2] >> sh) & 0xff) << 16) | ((sm[base+3] >> sh) << 24);
            }
            od[j] = val;
        }
    } else if (bid < HH * NB + 2 * NB) {
        const int z = bid - HH * NB;
        const int n = z >> 1, hidx = (z & 1) ? (HP - 1) : 0;
        int* od = (int*)xp2 + (n * HP + hidx) * (WP * CI / 4);
        #pragma unroll
        for (int it = 0; it < 8; ++it) od[tid + it * 256] = 0;
    } else {
        // ---- pack w for one co + BG[co][9]; B layout: 4-KB (t,c64,q) units,
        // co 0..255 x 16 B inside each unit ----
        const int co = bid - (HH * NB + 2 * NB);
        for (int j = tid; j < 1152; j += 256) sm[j] = wgt[co * 1152 + j];  // [ci][9]
        __syncthreads();
        for (int j = tid; j < 288; j += 256) {      // 9t x 2c64 x 4q x 4j4
            int j4 = j & 3, q = (j >> 2) & 3, c64 = (j >> 4) & 1, t = j >> 5;
            int ci = c64 * 64 + q * 16 + j4 * 4;
            int b0 = sm[(ci + 0) * 9 + t] & 255, b1 = sm[(ci + 1) * 9 + t] & 255;
            int b2 = sm[(ci + 2) * 9 + t] & 255, b3 = sm[(ci + 3) * 9 + t];
            ((int*)bp)[((t * 2 + c64) * 4 + q) * 1024 + co * 4 + j4] =
                b0 | (b1 << 8) | (b2 << 16) | (b3 << 24);
        }
        if (tid < 9) {
            int s = 0;
            for (int ci = 0; ci < CI; ++ci) s += sm[ci * 9 + tid];
            sm[1152 + tid] = s;
        }
        __syncthreads();
        if (tid < 9) {
            int hc = tid / 3, wc = tid - hc * 3;
            int dlo = (hc == 0) ? 1 : 0, dhi = (hc == 2) ? 1 : 2;
            int clo = (wc == 0) ? 1 : 0, chi = (wc == 2) ? 1 : 2;
            int s = 0;
            for (int dr = dlo; dr <= dhi; ++dr)
                for (int dc = clo; dc <= chi; ++dc) s += sm[1152 + dr * 3 + dc];
            BG[co * 9 + tid] = bias[co] - (*zpi) * s;
        }
    }
}

// ---- main: block = 128 M x 64 co, 4 waves of 32 M x 64 co; barrier-free K ----
__global__ __launch_bounds__(256, 2) void qconv_mfma(
    const int8_t* __restrict__ xp2, const int8_t* __restrict__ bp,
    const int* __restrict__ BG,
    const float* __restrict__ si, const float* __restrict__ sw,
    const float* __restrict__ so, const int* __restrict__ zpo,
    int* __restrict__ out)
{
    const int tid  = threadIdx.x, lane = tid & 63, wid = tid >> 6;
    const int quad = lane >> 4, lo16 = lane & 15;
    // XCD swizzle: blocks sharing an M-range (4 co-blocks) land on one XCD.
    const int bid  = blockIdx.x;
    const int xcd  = bid & 7, co64 = (bid >> 3) & 3, mi = bid >> 5;  // mi 0..97
    const int m_idx  = xcd * 98 + mi;               // 0..783
    const int mbase  = m_idx * 128 + wid * 32;
    const int cobase = co64 * 64;

    __shared__ char smem[72 * 1024];        // B: 72 x 1-KB units; epilogue aliases

    #pragma unroll
    for (int k = 0; k < 18; ++k) {          // stage block's B slice (72 KB)
        const int u = wid + 4 * k;          // 0..71 = (t*2+c)*4+q
        __builtin_amdgcn_global_load_lds(
            (const __attribute__((address_space(1))) void*)
                (bp + u * 4096 + cobase * 16 + lane * 16),
            (__attribute__((address_space(3))) void*)(smem + (u << 10)),
            16, 0, 0);
    }

    const int nS   = mbase / SPA;           // wave-uniform (32 | 3136)
    const int remS = mbase - nS * SPA;
    int base0[2];
    #pragma unroll
    for (int mt = 0; mt < 2; ++mt) {        // padded addr of tap (dr=0,dc=0)
        const int rm = remS + mt * 16 + lo16;
        const int h = rm / WW, w = rm - h * WW;
        base0[mt] = ((nS * HP + h) * WP + w) * 128 + quad * 16;
    }

    v4i acc[2][4];
    #pragma unroll
    for (int mt = 0; mt < 2; ++mt)
        #pragma unroll
        for (int ct = 0; ct < 4; ++ct) acc[mt][ct] = (v4i){0, 0, 0, 0};

    // 3-tap row-group A pipeline, double-buffered (12 loads in flight)
    v4i aT[2][3][2][2];
    #pragma unroll
    for (int tp = 0; tp < 3; ++tp)
        #pragma unroll
        for (int mt = 0; mt < 2; ++mt) {
            const int off = tp * 128;               // dr=0 row
            aT[0][tp][mt][0] = *(const v4i*)(xp2 + base0[mt] + off);
            aT[0][tp][mt][1] = *(const v4i*)(xp2 + base0[mt] + off + 64);
        }
    __syncthreads();                        // B staged

    #pragma unroll
    for (int g = 0; g < 3; ++g) {           // g = dr row group
        if (g < 2) {
            #pragma unroll
            for (int tp = 0; tp < 3; ++tp)
                #pragma unroll
                for (int mt = 0; mt < 2; ++mt) {
                    const int off = ((g + 1) * WP + tp) * 128;
                    aT[(g + 1) & 1][tp][mt][0] = *(const v4i*)(xp2 + base0[mt] + off);
                    aT[(g + 1) & 1][tp][mt][1] = *(const v4i*)(xp2 + base0[mt] + off + 64);
                }
        }
        #pragma unroll
        for (int tp = 0; tp < 3; ++tp) {
            const int t = g * 3 + tp;
            #pragma unroll
            for (int c = 0; c < 2; ++c) {
                const int ub = ((t * 2 + c) * 4 + quad) * 1024 + lo16 * 16;
                #pragma unroll
                for (int ct = 0; ct < 4; ++ct) {
                    v4i b = *(const v4i*)(smem + ub + ct * 256);
                    #pragma unroll
                    for (int mt = 0; mt < 2; ++mt)
                        acc[mt][ct] = __builtin_amdgcn_mfma_i32_16x16x64_i8(
                            aT[g & 1][tp][mt][c], b, acc[mt][ct], 0, 0, 0);
                }
            }
        }
    }

    // ---- epilogue: requant + LDS transpose (aliased onto dead B) ----
    const float rs = (*si) * (*sw) / (*so);
    const float zo = (float)(*zpo);

    __syncthreads();                        // all waves done reading B
    int* lt = (int*)smem + wid * 2176;      // 64 co x 34-dword rows per wave

    #pragma unroll
    for (int mt = 0; mt < 2; ++mt) {
        int cls[4];
        #pragma unroll
        for (int i = 0; i < 4; ++i) {
            const int rm = remS + mt * 16 + quad * 4 + i;   // C/D row = quad*4+i
            const int h2 = rm / WW, w2 = rm - h2 * WW;
            const int hc = (h2 == 0) ? 0 : ((h2 == HH - 1) ? 2 : 1);
            const int wc = (w2 == 0) ? 0 : ((w2 == WW - 1) ? 2 : 1);
            cls[i] = hc * 3 + wc;
        }
        #pragma unroll
        for (int ct = 0; ct < 4; ++ct) {
            const int co = cobase + ct * 16 + lo16;         // C/D col = lane&15
            v4i vv;
            #pragma unroll
            for (int i = 0; i < 4; ++i) {
                int a = acc[mt][ct][i] + BG[co * 9 + cls[i]];
                float y = rintf((float)a * rs + zo);
                y = fminf(fmaxf(y, -128.f), 127.f);
                vv[i] = (int)y;
            }
            *(v4i*)(lt + (ct * 16 + lo16) * 34 + mt * 16 + quad * 4) = vv;
        }
    }
    // same-wave ds_write -> ds_read: in-order, no barrier

    #pragma unroll
    for (int cc = 0; cc < 8; ++cc) {
        const int col = cc * 8 + (lane >> 3);               // co_local 0..63
        const int m4  = (lane & 7) * 4;                     // 128-B runs
        v4i v = *(const v4i*)(lt + col * 34 + m4);
        const int oidx = (nS * CO + cobase + col) * SPA + remS + m4;
        *(v4i*)(out + oidx) = v;
    }
}

extern "C" void kernel_launch(void* const* d_in, const int* in_sizes, int n_in,
                              void* d_out, int out_size, void* d_ws, size_t ws_size,
                              hipStream_t stream) {
    const int*   x    = (const int*)d_in[0];
    const int*   wgt  = (const int*)d_in[1];
    const int*   bias = (const int*)d_in[2];
    const float* si   = (const float*)d_in[3];
    const float* sw   = (const float*)d_in[4];
    const float* so   = (const float*)d_in[5];
    const int*   zpi  = (const int*)d_in[6];
    const int*   zpo  = (const int*)d_in[7];
    int* out = (int*)d_out;

    int8_t* xp2 = (int8_t*)d_ws;
    int8_t* bp  = xp2 + XP2_BYTES;
    int*    bg  = (int*)(bp + BP_BYTES);

    prep_kernel<<<HH * NB + 2 * NB + CO, 256, 0, stream>>>(x, wgt, bias, zpi, xp2, bp, bg);
    qconv_mfma<<<8 * 4 * 98, 256, 0, stream>>>(xp2, bp, bg, si, sw, so, zpo, out);
}

// Round 10
// 202.094 us; speedup vs baseline: 1.3356x; 1.1429x over previous
//
#include <hip/hip_runtime.h>
#include <stdint.h>

// QuantizedConv2d int8 implicit GEMM via MFMA i32_16x16x64_i8.
// N=32, C_in=128, H=W=56, C_out=256, 3x3, pad 1, stride 1.
// Output int8 values stored as int32 (harness reads integer outputs as np.int32).
//
// R10 = R9 with the swizzle-carry bug fixed: logical P+64 maps to phys(P)^64,
// NOT phys(P)+64 (the 3-bit XOR swizzle can set bit 6 of phys; +64 then
// carries into the next 128-B unit -> R9's absmax=255 on half the w columns).
// Design: A slab (8 output rows + halo = 10 padded rows, 80 KB) in LDS staged
// once; B (72 KB) in LDS, per-tap fragments hoisted to registers; 112 M/wave
// (504 MFMA). Pad value = zp -> border correction is cls-independent.

#define NB 32
#define CI 128
#define HH 56
#define WW 56
#define CO 256
#define SPA (HH * WW)              // 3136 = 7 blocks x 448 (8 image rows each)
#define HP 58
#define WP 64
#define XP2_BYTES (NB * HP * WP * CI)      // 15204352
#define BP_BYTES (9 * 2 * 4 * CO * 16)     // 294912

typedef int v4i __attribute__((ext_vector_type(4)));

// ---- prep ----
// [0,1792): pack one (n,h) row -> padded NHWC int8, pad byte = zp, XOR-swizzled
// [1792,1856): border h-rows = zp
// [1856,2112): weight pack + BG[co] = bias - zp*S9
__global__ __launch_bounds__(256) void prep_kernel(
    const int* __restrict__ x, const int* __restrict__ wgt,
    const int* __restrict__ bias, const int* __restrict__ zpi,
    int8_t* __restrict__ xp2, int8_t* __restrict__ bp, int* __restrict__ BG)
{
    __shared__ int sm[1824];
    const int tid = threadIdx.x, bid = blockIdx.x;
    const int zp = *zpi;
    const int zp4 = (zp & 255) * 0x01010101;

    if (bid < HH * NB) {
        const int n = bid / HH, h = bid % HH;
        #pragma unroll
        for (int it = 0; it < 7; ++it) {
            int j = tid + it * 256;                 // 1792 = 128 ci x 14 w4
            int ci = j / 14, w4 = j - ci * 14;
            const v4i v = *(const v4i*)(x + ((n * CI + ci) * HH + h) * WW + w4 * 4);
            sm[w4 * 130 + ci] = (v.x & 255) | ((v.y & 255) << 8) |
                                ((v.z & 255) << 16) | (v.w << 24);
        }
        __syncthreads();
        int* od = (int*)xp2 + (n * HP + h + 1) * (WP * CI / 4);  // 2048 dwords
        #pragma unroll
        for (int it = 0; it < 8; ++it) {
            int j = tid + it * 256;                 // j = widx*32 + ci4
            int widx = j >> 5, ci4 = j & 31;
            int val = zp4;                          // pad value = zp
            if (widx >= 1 && widx <= WW) {
                int w = widx - 1;
                int base = (w >> 2) * 130 + ci4 * 4;
                int sh = (w & 3) * 8;
                val = ((sm[base] >> sh) & 0xff) | (((sm[base+1] >> sh) & 0xff) << 8) |
                      (((sm[base+2] >> sh) & 0xff) << 16) | ((sm[base+3] >> sh) << 24);
            }
            od[j ^ ((widx & 7) << 2)] = val;        // XOR-swizzle 16-B units
        }
    } else if (bid < HH * NB + 2 * NB) {
        const int z = bid - HH * NB;
        const int n = z >> 1, hidx = (z & 1) ? (HP - 1) : 0;
        int* od = (int*)xp2 + (n * HP + hidx) * (WP * CI / 4);
        #pragma unroll
        for (int it = 0; it < 8; ++it) od[tid + it * 256] = zp4;  // zp border rows
    } else {
        const int co = bid - (HH * NB + 2 * NB);
        for (int j = tid; j < 1152; j += 256) sm[j] = wgt[co * 1152 + j];  // [ci][9]
        __syncthreads();
        for (int j = tid; j < 288; j += 256) {      // 9t x 2c64 x 4q x 4j4
            int j4 = j & 3, q = (j >> 2) & 3, c64 = (j >> 4) & 1, t = j >> 5;
            int ci = c64 * 64 + q * 16 + j4 * 4;
            int b0 = sm[(ci + 0) * 9 + t] & 255, b1 = sm[(ci + 1) * 9 + t] & 255;
            int b2 = sm[(ci + 2) * 9 + t] & 255, b3 = sm[(ci + 3) * 9 + t];
            ((int*)bp)[((t * 2 + c64) * 4 + q) * 1024 + co * 4 + j4] =
                b0 | (b1 << 8) | (b2 << 16) | (b3 << 24);
        }
        if (tid < 9) {
            int s = 0;
            for (int ci = 0; ci < CI; ++ci) s += sm[ci * 9 + tid];
            sm[1152 + tid] = s;
        }
        __syncthreads();
        if (tid == 0) {
            int s9 = 0;
            for (int t = 0; t < 9; ++t) s9 += sm[1152 + t];
            BG[co] = bias[co] - zp * s9;            // cls-independent correction
        }
    }
}

// ---- main: block = 448 M (8 rows) x 64 co; 4 waves of 112 M x 64 co ----
__global__ __launch_bounds__(256, 1) void qconv_mfma(
    const int8_t* __restrict__ xp2, const int8_t* __restrict__ bp,
    const int* __restrict__ BG,
    const float* __restrict__ si, const float* __restrict__ sw,
    const float* __restrict__ so, const int* __restrict__ zpo,
    int* __restrict__ out)
{
    const int tid  = threadIdx.x, lane = tid & 63, wid = tid >> 6;
    const int quad = lane >> 4, lo16 = lane & 15;
    const int bid  = blockIdx.x;                    // 896 blocks
    const int xcd  = bid & 7, idx = bid >> 3;
    const int co64 = idx & 3, slab = idx >> 2;      // slab 0..27 per XCD-slot
    const int gslab = xcd * 28 + slab;              // 0..223 = 32 n x 7 blk8
    const int n = gslab / 7, blk8 = gslab % 7;
    const int cobase = co64 * 64;
    const int p0   = blk8 * 8;                      // padded slab top row
    const int remS = blk8 * 448;

    __shared__ __attribute__((aligned(16))) char smem[152 * 1024];
    char* Asm = smem;                               // 80 KB A slab (10 rows)
    char* Bsm = smem + 80 * 1024;                   // 72 KB B

    const int8_t* aslab = xp2 + (((size_t)n * HP + p0) << 13);  // *8192
    #pragma unroll
    for (int k = 0; k < 20; ++k) {                  // A: 80 x 1-KB units
        const int u = wid + 4 * k;
        __builtin_amdgcn_global_load_lds(
            (const __attribute__((address_space(1))) void*)(aslab + (u << 10) + lane * 16),
            (__attribute__((address_space(3))) void*)(Asm + (u << 10)), 16, 0, 0);
    }
    #pragma unroll
    for (int k = 0; k < 18; ++k) {                  // B: 72 x 1-KB units
        const int u = wid + 4 * k;
        __builtin_amdgcn_global_load_lds(
            (const __attribute__((address_space(1))) void*)(bp + (u << 12) + cobase * 16 + lane * 16),
            (__attribute__((address_space(3))) void*)(Bsm + (u << 10)), 16, 0, 0);
    }

    int abase[7];
    const int mw = wid * 112;
    #pragma unroll
    for (int mt = 0; mt < 7; ++mt) {                // logical slab addr, tap (0,0)
        const int ml = mw + mt * 16 + lo16;         // 0..447
        const int srow = ml / 56, scol = ml - srow * 56;
        abase[mt] = (srow * WP + scol) * 128 + quad * 16;
    }

    int bgv[4];
    #pragma unroll
    for (int ct = 0; ct < 4; ++ct) bgv[ct] = BG[cobase + ct * 16 + lo16];
    const float rs = (*si) * (*sw) / (*so);
    const float zo = (float)(*zpo);

    v4i acc[7][4];
    #pragma unroll
    for (int mt = 0; mt < 7; ++mt)
        #pragma unroll
        for (int ct = 0; ct < 4; ++ct) acc[mt][ct] = (v4i){0, 0, 0, 0};

    __syncthreads();                                // staging drained

    #pragma unroll
    for (int t = 0; t < 9; ++t) {
        const int toff = ((t / 3) * WP + (t % 3)) * 128;
        v4i b[2][4];                                // B for this tap -> registers
        #pragma unroll
        for (int c = 0; c < 2; ++c)
            #pragma unroll
            for (int ct = 0; ct < 4; ++ct)
                b[c][ct] = *(const v4i*)(Bsm + ((t * 2 + c) * 4 + quad) * 1024 +
                                         lo16 * 16 + ct * 256);
        #pragma unroll
        for (int mt = 0; mt < 7; ++mt) {
            const int P = abase[mt] + toff;         // bit 6 of P is always 0
            const int phys = P ^ (((P >> 7) & 7) << 4);   // match prep swizzle
            v4i a0 = *(const v4i*)(Asm + phys);           // logical ci 0..63
            v4i a1 = *(const v4i*)(Asm + (phys ^ 64));    // logical P+64 -> phys^64
            #pragma unroll
            for (int ct = 0; ct < 4; ++ct)
                acc[mt][ct] = __builtin_amdgcn_mfma_i32_16x16x64_i8(a0, b[0][ct], acc[mt][ct], 0, 0, 0);
            #pragma unroll
            for (int ct = 0; ct < 4; ++ct)
                acc[mt][ct] = __builtin_amdgcn_mfma_i32_16x16x64_i8(a1, b[1][ct], acc[mt][ct], 0, 0, 0);
        }
    }

    // ---- epilogue: requant + per-mt LDS transpose (aliased onto dead A) ----
    __syncthreads();                                // all waves past K-loop
    int* lt = (int*)smem + wid * 1088;              // 64 co x 17 dwords per wave

    #pragma unroll
    for (int mt = 0; mt < 7; ++mt) {
        #pragma unroll
        for (int ct = 0; ct < 4; ++ct) {
            v4i vv;
            #pragma unroll
            for (int i = 0; i < 4; ++i) {           // C/D row = quad*4+i
                float y = rintf((float)(acc[mt][ct][i] + bgv[ct]) * rs + zo);
                y = fminf(fmaxf(y, -128.f), 127.f);
                vv[i] = (int)y;
            }
            *(v4i*)(lt + (ct * 16 + lo16) * 17 + quad * 4) = vv;
        }
        // same-wave ds_write -> ds_read: in-order, no barrier
        const int rm0 = remS + mw + mt * 16;
        #pragma unroll
        for (int it = 0; it < 4; ++it) {
            const int col = it * 16 + (lane >> 2);  // co_local 0..63
            const int m4  = (lane & 3) * 4;         // 4 lanes x 16 B = 64-B runs
            v4i v = *(const v4i*)(lt + col * 17 + m4);
            *(v4i*)(out + ((n * CO + cobase + col) * SPA + rm0 + m4)) = v;
        }
        // next mt reuses lt: same-wave in-order, safe
    }
}

extern "C" void kernel_launch(void* const* d_in, const int* in_sizes, int n_in,
                              void* d_out, int out_size, void* d_ws, size_t ws_size,
                              hipStream_t stream) {
    const int*   x    = (const int*)d_in[0];
    const int*   wgt  = (const int*)d_in[1];
    const int*   bias = (const int*)d_in[2];
    const float* si   = (const float*)d_in[3];
    const float* sw   = (const float*)d_in[4];
    const float* so   = (const float*)d_in[5];
    const int*   zpi  = (const int*)d_in[6];
    const int*   zpo  = (const int*)d_in[7];
    int* out = (int*)d_out;

    int8_t* xp2 = (int8_t*)d_ws;
    int8_t* bp  = xp2 + XP2_BYTES;
    int*    bg  = (int*)(bp + BP_BYTES);

    prep_kernel<<<HH * NB + 2 * NB + CO, 256, 0, stream>>>(x, wgt, bias, zpi, xp2, bp, bg);
    qconv_mfma<<<896, 256, 0, stream>>>(xp2, bp, bg, si, sw, so, zpo, out);
}